// Round 9
// baseline (487.967 us; speedup 1.0000x reference)
//
#include <hip/hip_runtime.h>

// Convolution_1228360646680 — equivariant graph conv, edge-range segmented version
// N=25000, E=400000, MUL=32, NSC=8, HID=64
//
// Fast path:
//   prep:     scaled W1s (8x64 f32), W2T (fallback), W2Tb (128x64 bf16)
//   node_in:  xsv1[n][128] = a[n]/sqrt(32) * (x @ w1)
//   CSR sort: count -> scan -> scatter (esrc/eattr/escal/dst into dst-sorted order)
//   pad_init: pad edge arrays to 256-multiple (dst=scratch row, zero payload) + sentinel
//   fused_seg: block = 256-edge range; per 16-edge chunk:
//       A: 256 threads h=silu(q@W1s) -> LDS (W1s register-resident)
//       B: per wave 4 MFMAs -> 4KB LDS w-tile (validated bijection)
//       C: consumer accumulates features, flushes to mid[dst] via coalesced
//          atomicAdd when uniform dst changes (segmented reduction)
//   node_out: out[n][128] = b[n]/sqrt(64)/sqrt(16) * (mid @ w2)
// Fallback: atomic scatter-add + node_out if ws too small.

typedef __attribute__((ext_vector_type(8))) short bf16x8;
typedef __attribute__((ext_vector_type(4))) float f32x4;

__device__ __forceinline__ unsigned bf16r(float x) {
    unsigned u = __float_as_uint(x);
    return (u + 0x7fffu + ((u >> 16) & 1u)) >> 16;   // RNE
}

__global__ __launch_bounds__(256) void prep_kernel(
    const float* __restrict__ Wfc1, const float* __restrict__ Wfc2,
    float* __restrict__ W1s, float* __restrict__ W2T, unsigned short* __restrict__ W2Tb)
{
    int t = blockIdx.x * 256 + threadIdx.x;
    const float inv_sqrt_nsc = 0.35355339059327373f; // 1/sqrt(8)
    if (t < 8 * 64) W1s[t] = Wfc1[t] * inv_sqrt_nsc;
    if (t < 64 * 128) {
        int r = t >> 7, c = t & 127;
        float v = Wfc2[t] * 0.125f;                  // 1/sqrt(64)
        W2T[c * 64 + r] = v;
        W2Tb[c * 64 + r] = (unsigned short)bf16r(v);
    }
}

__global__ __launch_bounds__(256) void node_in_kernel(
    const float* __restrict__ node_input, const float* __restrict__ attr_in,
    const float* __restrict__ w1s, const float* __restrict__ w1v,
    float* __restrict__ xsv1, int n_nodes)
{
    __shared__ float sWs[1024], sWv[1024], srow[2][128];
    for (int k = threadIdx.x; k < 1024; k += 256) { sWs[k] = w1s[k]; sWv[k] = w1v[k]; }
    int j = threadIdx.x & 127;
    int half = threadIdx.x >> 7;
    int w = 0, i = 0;
    if (j >= 32) { int jj = j - 32; w = jj / 3; i = jj - 3 * w; }
    const float inv1 = 0.17677669529663687f; // 1/sqrt(32)
    for (int base = blockIdx.x * 2; base < n_nodes; base += gridDim.x * 2) {
        int n = base + half;
        __syncthreads();
        if (n < n_nodes) srow[half][j] = node_input[(size_t)n * 128 + j];
        __syncthreads();
        if (n < n_nodes) {
            float acc = 0.0f;
            if (j < 32) {
                #pragma unroll
                for (int u = 0; u < 32; u++) acc += srow[half][u] * sWs[u * 32 + j];
            } else {
                #pragma unroll
                for (int u = 0; u < 32; u++) acc += srow[half][32 + 3 * u + i] * sWv[u * 32 + w];
            }
            xsv1[(size_t)n * 128 + j] = acc * (attr_in[n] * inv1);
        }
    }
}

// ---------------- CSR build ----------------
__global__ __launch_bounds__(256) void count_kernel(
    const int* __restrict__ edst, int* __restrict__ counts, int n_edges)
{
    int e = blockIdx.x * 256 + threadIdx.x;
    if (e < n_edges) atomicAdd(&counts[edst[e]], 1);
}

__global__ __launch_bounds__(1024) void scan_kernel(
    const int* __restrict__ counts, int* __restrict__ offs, int* __restrict__ cursor, int n)
{
    __shared__ int part[1024];
    int tid = threadIdx.x;
    int chunk = (n + 1023) / 1024;
    int begin = tid * chunk;
    int end = begin + chunk; if (end > n) end = n;
    int s = 0;
    for (int i = begin; i < end; i++) s += counts[i];
    part[tid] = s;
    __syncthreads();
    for (int off = 1; off < 1024; off <<= 1) {
        int v = (tid >= off) ? part[tid - off] : 0;
        __syncthreads();
        part[tid] += v;
        __syncthreads();
    }
    int base = (tid == 0) ? 0 : part[tid - 1];
    for (int i = begin; i < end; i++) {
        offs[i] = base; cursor[i] = base;
        base += counts[i];
    }
    if (tid == 1023) offs[n] = part[1023];
}

__global__ __launch_bounds__(256) void scatter_kernel(
    const int* __restrict__ edst, const int* __restrict__ esrc,
    const float* __restrict__ eattr, const float* __restrict__ escal,
    int* __restrict__ cursor,
    int* __restrict__ esrc_s, float4* __restrict__ eattr_s, float4* __restrict__ escal_s,
    int* __restrict__ dst_s, int n_edges)
{
    int e = blockIdx.x * 256 + threadIdx.x;
    if (e < n_edges) {
        int d = edst[e];
        int p = atomicAdd(&cursor[d], 1);
        esrc_s[p] = esrc[e];
        dst_s[p] = d;
        eattr_s[p] = *reinterpret_cast<const float4*>(eattr + (size_t)e * 4);
        escal_s[2 * (size_t)p]     = *reinterpret_cast<const float4*>(escal + (size_t)e * 8);
        escal_s[2 * (size_t)p + 1] = *reinterpret_cast<const float4*>(escal + (size_t)e * 8 + 4);
    }
}

// pad edge arrays [n_edges, n_pad) and write sentinel dst_s[n_pad] = -1
__global__ __launch_bounds__(256) void pad_init_kernel(
    int* __restrict__ esrc_s, float4* __restrict__ eattr_s, float4* __restrict__ escal_s,
    int* __restrict__ dst_s, int n_edges, int n_pad, int n_nodes)
{
    int k = n_edges + threadIdx.x;
    float4 z = make_float4(0.f, 0.f, 0.f, 0.f);
    if (k < n_pad) {
        esrc_s[k] = 0;
        dst_s[k] = n_nodes;            // scratch row
        eattr_s[k] = z;
        escal_s[2 * (size_t)k] = z;
        escal_s[2 * (size_t)k + 1] = z;
    }
    if (threadIdx.x == 0) dst_s[n_pad] = -1;   // sentinel: forces final flush
}

// ---------------- fused edge-range kernel: MLP(MFMA) + segmented gather ----------------
__global__ __launch_bounds__(256) void fused_seg_kernel(
    const float4* __restrict__ escal_s, const float* __restrict__ W1s_g,
    const unsigned short* __restrict__ W2Tb,
    const float* __restrict__ xsv1, const int* __restrict__ esrc_s,
    const float4* __restrict__ eattr_s, const int* __restrict__ dst_s,
    float* __restrict__ mid)
{
    __shared__ unsigned short h_lds[16][72];   // bf16 h-tile, 144B rows (bank-clean pad)
    __shared__ unsigned short w_lds[8 * 256];  // 4KB w-tile, validated tile bijection

    int tid = threadIdx.x;
    int wv_ = tid >> 6, l = tid & 63;
    int lm = l & 15, lk = l >> 4;

    // B-fragments: this wave's two col-tiles, register-resident
    bf16x8 bfr[2][2];
    #pragma unroll
    for (int tt = 0; tt < 2; tt++) {
        int t = 2 * wv_ + tt;
        int nn = t * 16 + lm;
        bfr[tt][0] = *reinterpret_cast<const bf16x8*>(W2Tb + nn * 64 + lk * 8);
        bfr[tt][1] = *reinterpret_cast<const bf16x8*>(W2Tb + nn * 64 + lk * 8 + 32);
    }

    // phase-A decode + register-resident W1s rows for this thread's 4 k-columns
    int eA = tid & 15, kq = tid >> 4;
    float4 w1r[8];
    #pragma unroll
    for (int in_ = 0; in_ < 8; in_++)
        w1r[in_] = *reinterpret_cast<const float4*>(W1s_g + in_ * 64 + kq * 4);

    // consumer feature decode (validated mapping)
    int kind, u = 0, i = 0, col;
    if (tid < 32)       { kind = 0; u = tid;       col = tid; }
    else if (tid < 64)  { kind = 1; u = tid - 32;  col = 96 + u; }
    else if (tid < 160) { int q = tid - 64;  u = q / 3; i = q - 3 * u; kind = 2; col = 32 + u; }
    else                { int q = tid - 160; u = q / 3; i = q - 3 * u; kind = 3; col = 64 + u; }
    const int wbase = ((col >> 4) << 8) + ((col & 15) << 2);
    const float inv_sqrt3 = 0.5773502691896258f;

    int e0 = blockIdx.x * 256;
    float acc = 0.0f;
    int dcur = dst_s[e0];

    for (int ck = 0; ck < 16; ck++) {
        int k0 = e0 + ck * 16;

        // ---- phase A: h[e][k] = silu(q[e] @ W1s[:,k])
        {
            float4 qa = escal_s[2 * (size_t)(k0 + eA)];
            float4 qb = escal_s[2 * (size_t)(k0 + eA) + 1];
            float q[8] = {qa.x, qa.y, qa.z, qa.w, qb.x, qb.y, qb.z, qb.w};
            float h0 = 0.f, h1 = 0.f, h2 = 0.f, h3 = 0.f;
            #pragma unroll
            for (int in_ = 0; in_ < 8; in_++) {
                h0 += q[in_] * w1r[in_].x; h1 += q[in_] * w1r[in_].y;
                h2 += q[in_] * w1r[in_].z; h3 += q[in_] * w1r[in_].w;
            }
            h0 = h0 / (1.0f + __expf(-h0));
            h1 = h1 / (1.0f + __expf(-h1));
            h2 = h2 / (1.0f + __expf(-h2));
            h3 = h3 / (1.0f + __expf(-h3));
            unsigned d0 = bf16r(h0) | (bf16r(h1) << 16);
            unsigned d1 = bf16r(h2) | (bf16r(h3) << 16);
            *reinterpret_cast<uint2*>(reinterpret_cast<char*>(&h_lds[0][0]) + eA * 144 + kq * 8)
                = make_uint2(d0, d1);
        }
        __syncthreads();

        // ---- phase B: 4 MFMAs per wave -> w_lds
        {
            const char* hb = reinterpret_cast<const char*>(&h_lds[0][0]);
            bf16x8 af0 = *reinterpret_cast<const bf16x8*>(hb + lm * 144 + lk * 16);
            bf16x8 af1 = *reinterpret_cast<const bf16x8*>(hb + lm * 144 + 64 + lk * 16);
            #pragma unroll
            for (int tt = 0; tt < 2; tt++) {
                f32x4 a4 = {0.f, 0.f, 0.f, 0.f};
                a4 = __builtin_amdgcn_mfma_f32_16x16x32_bf16(af0, bfr[tt][0], a4, 0, 0, 0);
                a4 = __builtin_amdgcn_mfma_f32_16x16x32_bf16(af1, bfr[tt][1], a4, 0, 0, 0);
                unsigned s0 = bf16r(a4[0]) | (bf16r(a4[1]) << 16);
                unsigned s1 = bf16r(a4[2]) | (bf16r(a4[3]) << 16);
                *reinterpret_cast<uint2*>(&w_lds[(2 * wv_ + tt) * 256 + l * 4]) = make_uint2(s0, s1);
            }
        }
        __syncthreads();

        // ---- consumer: w-col into regs, segmented accumulate, flush on dst change
        {
            unsigned wr[8];
            #pragma unroll
            for (int g = 0; g < 4; g++) {
                uint2 v = *reinterpret_cast<const uint2*>(&w_lds[wbase + g * 64]);
                wr[2 * g] = v.x; wr[2 * g + 1] = v.y;
            }
            #pragma unroll
            for (int c = 0; c < 16; c++) {
                int k = k0 + c;
                unsigned d = wr[c >> 1];
                float wvv = (c & 1) ? __uint_as_float(d & 0xffff0000u)
                                    : __uint_as_float(d << 16);
                int src = esrc_s[k];
                float4 ea = eattr_s[k];
                const float* __restrict__ nb = xsv1 + (size_t)src * 128;
                if (kind == 0)      acc += wvv * nb[u] * ea.x;
                else if (kind == 1) acc += wvv * (nb[32 + 3 * u] * ea.y + nb[33 + 3 * u] * ea.z
                                                  + nb[34 + 3 * u] * ea.w) * inv_sqrt3;
                else if (kind == 2) { float yvi = (i == 0) ? ea.y : (i == 1) ? ea.z : ea.w;
                                      acc += wvv * nb[u] * yvi; }
                else                acc += wvv * ea.x * nb[32 + 3 * u + i];
                int dn = dst_s[k + 1];
                if (dn != dcur) {
                    atomicAdd(mid + (size_t)dcur * 256 + tid, acc);
                    acc = 0.0f;
                    dcur = dn;
                }
            }
        }
        // A(i+1) writes h_lds (read by B(i) before last barrier); consumer reads
        // w_lds concurrently with A(i+1) — disjoint. bar1 then fences B(i+1). Safe.
    }
    if (dcur >= 0) atomicAdd(mid + (size_t)dcur * 256 + tid, acc);
}

// ---------------- fallback atomic edge kernel (ws too small) ----------------
__global__ __launch_bounds__(256) void edge_kernel_atomic(
    const float* __restrict__ xsv1, const int* __restrict__ esrc, const int* __restrict__ edst,
    const float* __restrict__ eattr, const float* __restrict__ escal,
    const float* __restrict__ W1s, const float* __restrict__ W2T,
    float* __restrict__ mid, int n_edges)
{
    int e = blockIdx.x * 256 + threadIdx.x;
    if (e >= n_edges) return;
    const float4 qa = *reinterpret_cast<const float4*>(escal + (size_t)e * 8);
    const float4 qb = *reinterpret_cast<const float4*>(escal + (size_t)e * 8 + 4);
    float h[64];
    #pragma unroll
    for (int t = 0; t < 64; t++) {
        float acc = qa.x * W1s[t]       + qa.y * W1s[64 + t]
                  + qa.z * W1s[128 + t] + qa.w * W1s[192 + t]
                  + qb.x * W1s[256 + t] + qb.y * W1s[320 + t]
                  + qb.z * W1s[384 + t] + qb.w * W1s[448 + t];
        h[t] = acc / (1.0f + __expf(-acc));
    }
    int src = esrc[e], dst = edst[e];
    const float4 ea = *reinterpret_cast<const float4*>(eattr + (size_t)e * 4);
    const float ys = ea.x, yv0 = ea.y, yv1 = ea.z, yv2 = ea.w;
    const float* __restrict__ nb = xsv1 + (size_t)src * 128;
    float* __restrict__ op = mid + (size_t)dst * 256;
    const float inv_sqrt3 = 0.5773502691896258f;
    for (int u = 0; u < 32; u++) {
        float w0 = 0.f, w1 = 0.f, w2 = 0.f, w3 = 0.f;
        const float* __restrict__ r0 = W2T + (size_t)u * 64;
        const float* __restrict__ r1 = W2T + (size_t)(32 + u) * 64;
        const float* __restrict__ r2 = W2T + (size_t)(64 + u) * 64;
        const float* __restrict__ r3 = W2T + (size_t)(96 + u) * 64;
        #pragma unroll
        for (int t = 0; t < 64; t++) {
            float hv = h[t];
            w0 += hv * r0[t]; w1 += hv * r1[t]; w2 += hv * r2[t]; w3 += hv * r3[t];
        }
        float es  = nb[u];
        float ev0 = nb[32 + 3 * u], ev1 = nb[33 + 3 * u], ev2 = nb[34 + 3 * u];
        atomicAdd(op + u,      w0 * es * ys);
        atomicAdd(op + 32 + u, w3 * (ev0 * yv0 + ev1 * yv1 + ev2 * yv2) * inv_sqrt3);
        float a1 = w1 * es;
        atomicAdd(op + 64 + 3 * u, a1 * yv0);
        atomicAdd(op + 65 + 3 * u, a1 * yv1);
        atomicAdd(op + 66 + 3 * u, a1 * yv2);
        float a2 = w2 * ys;
        atomicAdd(op + 160 + 3 * u, a2 * ev0);
        atomicAdd(op + 161 + 3 * u, a2 * ev1);
        atomicAdd(op + 162 + 3 * u, a2 * ev2);
    }
}

__global__ __launch_bounds__(256) void node_out_kernel(
    const float* __restrict__ mid, const float* __restrict__ attr_out,
    const float* __restrict__ w2s, const float* __restrict__ w2v,
    float* __restrict__ out, int n_nodes)
{
    __shared__ float sS0[1024], sS1[1024], sV0[1024], sV1[1024];
    for (int k = threadIdx.x; k < 1024; k += 256) {
        sS0[k] = w2s[k]; sS1[k] = w2s[1024 + k];
        sV0[k] = w2v[k]; sV1[k] = w2v[1024 + k];
    }
    __syncthreads();
    int j = threadIdx.x & 127;
    int half = threadIdx.x >> 7;
    int w = 0, i = 0;
    if (j >= 32) { int jj = j - 32; w = jj / 3; i = jj - 3 * w; }
    const float scale = 0.125f * 0.25f; // 1/sqrt(64) * 1/sqrt(16)
    for (int base = blockIdx.x * 2; base < n_nodes; base += gridDim.x * 2) {
        int n = base + half;
        if (n >= n_nodes) continue;
        const float* __restrict__ mr = mid + (size_t)n * 256;
        float acc = 0.0f;
        if (j < 32) {
            #pragma unroll
            for (int u = 0; u < 32; u++)
                acc += mr[u] * sS0[u * 32 + j] + mr[32 + u] * sS1[u * 32 + j];
        } else {
            #pragma unroll
            for (int u = 0; u < 32; u++)
                acc += mr[64 + 3 * u + i] * sV0[u * 32 + w] + mr[160 + 3 * u + i] * sV1[u * 32 + w];
        }
        out[(size_t)n * 128 + j] = acc * (attr_out[n] * scale);
    }
}

extern "C" void kernel_launch(void* const* d_in, const int* in_sizes, int n_in,
                              void* d_out, int out_size, void* d_ws, size_t ws_size,
                              hipStream_t stream)
{
    const float* node_input = (const float*)d_in[0];
    const float* attr_in    = (const float*)d_in[1];
    const float* attr_out   = (const float*)d_in[2];
    const int*   esrc       = (const int*)d_in[3];
    const int*   edst       = (const int*)d_in[4];
    const float* eattr      = (const float*)d_in[5];
    const float* escal      = (const float*)d_in[6];
    const float* w1s        = (const float*)d_in[7];
    const float* w1v        = (const float*)d_in[8];
    const float* Wfc1       = (const float*)d_in[9];
    const float* Wfc2       = (const float*)d_in[10];
    const float* w2s        = (const float*)d_in[11];
    const float* w2v        = (const float*)d_in[12];
    float* out = (float*)d_out;

    int n_nodes = in_sizes[0] / 128;
    int n_edges = in_sizes[3];
    int n_pad = ((n_edges + 255) / 256) * 256;
    int nblk = n_pad / 256;

    // workspace layout (aligned)
    char* p = (char*)d_ws;
    auto alloc = [&](size_t bytes, size_t align) -> void* {
        size_t a = (size_t)p; a = (a + align - 1) & ~(align - 1);
        p = (char*)a; void* r = (void*)p; p += bytes; return r;
    };
    float* xsv1 = (float*)alloc((size_t)n_nodes * 128 * 4, 16);
    float* W1s  = (float*)alloc(512 * 4, 16);
    float* W2T  = (float*)alloc(8192 * 4, 16);
    float* mid  = (float*)alloc((size_t)(n_nodes + 1) * 256 * 4, 16);
    int* counts = (int*)alloc((size_t)n_nodes * 4, 16);
    int* offs   = (int*)alloc(((size_t)n_nodes + 1) * 4, 16);
    int* cursor = (int*)alloc((size_t)n_nodes * 4, 16);
    int* esrc_s = (int*)alloc((size_t)n_pad * 4, 16);
    int* dst_s  = (int*)alloc(((size_t)n_pad + 1) * 4, 16);
    float4* eattr_s = (float4*)alloc((size_t)n_pad * 16, 16);
    float4* escal_s = (float4*)alloc((size_t)n_pad * 32, 16);
    unsigned short* W2Tb = (unsigned short*)alloc(8192 * 2, 64);
    size_t needed = (size_t)(p - (char*)d_ws);

    prep_kernel<<<32, 256, 0, stream>>>(Wfc1, Wfc2, W1s, W2T, W2Tb);
    node_in_kernel<<<2048, 256, 0, stream>>>(node_input, attr_in, w1s, w1v, xsv1, n_nodes);

    if (ws_size >= needed) {
        hipMemsetAsync(counts, 0, (size_t)n_nodes * sizeof(int), stream);
        hipMemsetAsync(mid, 0, (size_t)(n_nodes + 1) * 256 * sizeof(float), stream);
        count_kernel<<<(n_edges + 255) / 256, 256, 0, stream>>>(edst, counts, n_edges);
        scan_kernel<<<1, 1024, 0, stream>>>(counts, offs, cursor, n_nodes);
        scatter_kernel<<<(n_edges + 255) / 256, 256, 0, stream>>>(
            edst, esrc, eattr, escal, cursor, esrc_s, eattr_s, escal_s, dst_s, n_edges);
        pad_init_kernel<<<1, 256, 0, stream>>>(esrc_s, eattr_s, escal_s, dst_s,
                                               n_edges, n_pad, n_nodes);
        fused_seg_kernel<<<nblk, 256, 0, stream>>>(
            escal_s, W1s, W2Tb, xsv1, esrc_s, eattr_s, dst_s, mid);
        node_out_kernel<<<2048, 256, 0, stream>>>(mid, attr_out, w2s, w2v, out, n_nodes);
    } else {
        hipMemsetAsync(mid, 0, (size_t)(n_nodes + 1) * 256 * sizeof(float), stream);
        edge_kernel_atomic<<<(n_edges + 255) / 256, 256, 0, stream>>>(
            xsv1, esrc, edst, eattr, escal, W1s, W2T, mid, n_edges);
        node_out_kernel<<<2048, 256, 0, stream>>>(mid, attr_out, w2s, w2v, out, n_nodes);
    }
}